// Round 10
// baseline (2981.121 us; speedup 1.0000x reference)
//
#include <hip/hip_runtime.h>
#include <hip/hip_bf16.h>
#include <stdint.h>

#define BATCH 16
#define SEQ   2048
#define CH    1024
#define NH    16
#define NG    4
#define KW    5
#define GCH   256
#define DHD   64
#define NBG   (BATCH*NG)   // 64
#define NBH   (BATCH*NH)   // 256
#define MROWS (BATCH*SEQ)  // 32768

typedef __hip_bfloat16 bf16;
typedef float f32x4 __attribute__((ext_vector_type(4)));
typedef __bf16 bf16x8 __attribute__((ext_vector_type(8)));

__device__ __forceinline__ void unpack8(uint4 r, float* f){
    uint32_t w0=r.x,w1=r.y,w2=r.z,w3=r.w;
    f[0]=__uint_as_float(w0<<16); f[1]=__uint_as_float(w0&0xffff0000u);
    f[2]=__uint_as_float(w1<<16); f[3]=__uint_as_float(w1&0xffff0000u);
    f[4]=__uint_as_float(w2<<16); f[5]=__uint_as_float(w2&0xffff0000u);
    f[6]=__uint_as_float(w3<<16); f[7]=__uint_as_float(w3&0xffff0000u);
}

// ---------------------------------------------------------------------------
// fp32 -> bf16 convert, 8 elems/thread
// ---------------------------------------------------------------------------
__global__ __launch_bounds__(256)
void cvt_kernel(const float* __restrict__ in, bf16* __restrict__ out, int n)
{
    int i = (blockIdx.x*256 + threadIdx.x)*8;
    if (i >= n) return;
    float4 f0 = *(const float4*)(in+i);
    float4 f1 = *(const float4*)(in+i+4);
    union { bf16 b[8]; uint4 u; } pk;
    pk.b[0]=__float2bfloat16(f0.x); pk.b[1]=__float2bfloat16(f0.y);
    pk.b[2]=__float2bfloat16(f0.z); pk.b[3]=__float2bfloat16(f0.w);
    pk.b[4]=__float2bfloat16(f1.x); pk.b[5]=__float2bfloat16(f1.y);
    pk.b[6]=__float2bfloat16(f1.z); pk.b[7]=__float2bfloat16(f1.w);
    *(uint4*)(out+i) = pk.u;
}

// ---------------------------------------------------------------------------
// Weff[kk][cj] = sum_co w2[co] * W1[co][cj][kk];  wcst = {b2, dot(w2,b1)}
// ---------------------------------------------------------------------------
__global__ void prep_weff_kernel(const float* __restrict__ W1, const float* __restrict__ b1,
                                 const float* __restrict__ w2, const float* __restrict__ b2,
                                 float* __restrict__ weff, float* __restrict__ wcst)
{
    int kk = blockIdx.x;          // 0..4
    int cj = threadIdx.x;         // 0..255
    float s = 0.f;
    for (int co=0; co<GCH; ++co)
        s += w2[co] * W1[((size_t)co*GCH + cj)*KW + kk];
    weff[kk*GCH + cj] = s;
    if (kk==0 && cj==0){
        float sb = 0.f;
        for (int co=0; co<GCH; ++co) sb += w2[co]*b1[co];
        wcst[0] = b2[0];
        wcst[1] = sb;
    }
}

// ---------------------------------------------------------------------------
// 256x256-tile MFMA GEMM, BK=32, 2 LDS buffers = 64 KiB -> 2 BLOCKS/CU
// (TLP: co-resident block fills this block's drain gaps, m114 mechanism).
// Round-8-proven schedule, 1 barrier per K-tile:
//   iter t: STAGE(t+1 -> buf[cur^1])   (issue early)
//           ds_read buf[cur] (swizzled); lgkmcnt(0)
//           setprio(1); 32 MFMA; setprio(0)
//           vmcnt(0); s_barrier
// Race-free: the single barrier is preceded by BOTH vmcnt(0) (my STAGE(t+1)
// writes landed) and lgkmcnt(0) (my reads of buf[cur] done) in every wave,
// so after it: all writes of tile t+1 landed AND all reads of buf[cur]
// completed -> next iter may read buf[cur^1] and overwrite buf[cur].
// T2 swizzle (round-5-measured 0 conflicts): e = o ^ (((o>>7)&3)<<4) on
// 64B rows, same involution on staging global source and ds_read address.
// T1: 4 column-blocks of each A-panel grouped per XCD.
// MODE: 1 = bf16 [m][n]+rpb, 2 = bf16 transposed [b][n][l], 3 = f32 [m][n].
// ---------------------------------------------------------------------------
template<int MODE>
__global__ __launch_bounds__(512, 4)
void gemm256_kernel(const bf16* __restrict__ A, const bf16* __restrict__ Wb,
                    const float* __restrict__ bias, const float* __restrict__ rpb,
                    void* __restrict__ outp)
{
    __shared__ __bf16 SM[2*16384];   // 2 x (A 8192 + B 8192 elems) = 64 KiB
    const int t = threadIdx.x;
    const int w = t>>6, l = t&63;
    const int wrow = w>>2, wcol = w&3;     // 2 x 4 waves, 128x64 out each
    const int lr = l&15, kq = l>>4;        // kq: 0..3 (16B k-slot / acc row grp)

    const int lin = blockIdx.x;            // 0..511
    const int xcd = lin&7, sblk = lin>>3;
    const int m0 = (xcd*16 + (sblk>>2))*256;
    const int n0 = (sblk&3)*256;

    const bf16* Ag = A  + (size_t)m0*CH;
    const bf16* Bg = Wb + (size_t)n0*CH;

    // staging source map (round-5 verified): linear LDS byte o <- global swz(o)
    int srow[2], scol[2];
    #pragma unroll
    for (int r=0;r<2;++r){
        int o = (t + 512*r)*16;
        int e = o ^ (((o>>7)&3)<<4);
        srow[r] = e>>6;            // 64B rows (32 bf16)
        scol[r] = (e&63)>>1;
    }

    auto STAGE = [&](int tile, int buf){
        const int kt = tile*32;
        __bf16* ab = SM + buf*16384;
        __bf16* bb = ab + 8192;
        #pragma unroll
        for (int r=0;r<2;++r){
            __builtin_amdgcn_global_load_lds(
                (const __attribute__((address_space(1))) void*)(Ag + (size_t)srow[r]*CH + kt + scol[r]),
                (__attribute__((address_space(3))) void*)(ab + w*512 + r*4096), 16, 0, 0);
            __builtin_amdgcn_global_load_lds(
                (const __attribute__((address_space(1))) void*)(Bg + (size_t)srow[r]*CH + kt + scol[r]),
                (__attribute__((address_space(3))) void*)(bb + w*512 + r*4096), 16, 0, 0);
        }
    };

    f32x4 acc[8][4];
    #pragma unroll
    for (int i=0;i<8;++i)
        #pragma unroll
        for (int j=0;j<4;++j) acc[i][j] = (f32x4){0.f,0.f,0.f,0.f};

    STAGE(0, 0);
    asm volatile("s_waitcnt vmcnt(0)" ::: "memory");
    __builtin_amdgcn_s_barrier();
    __builtin_amdgcn_sched_barrier(0);

    const int NT = CH/32;   // 32
    for (int tt=0; tt<NT; ++tt){
        const int cur = tt&1;
        if (tt+1 < NT) STAGE(tt+1, cur^1);           // issue-early prefetch
        __builtin_amdgcn_sched_barrier(0);

        const __bf16* As_ = SM + cur*16384;
        const __bf16* Bs_ = As_ + 8192;
        bf16x8 af[8], bfr[4];
        #pragma unroll
        for (int fi=0; fi<8; ++fi){
            int row = wrow*128 + fi*16 + lr;
            int o = row*64 + kq*16;
            o ^= ((o>>7)&3)<<4;
            af[fi] = *(const bf16x8*)(As_ + (o>>1));
        }
        #pragma unroll
        for (int fj=0; fj<4; ++fj){
            int row = wcol*64 + fj*16 + lr;
            int o = row*64 + kq*16;
            o ^= ((o>>7)&3)<<4;
            bfr[fj] = *(const bf16x8*)(Bs_ + (o>>1));
        }
        asm volatile("s_waitcnt lgkmcnt(0)" ::: "memory");  // my reads in regs
        __builtin_amdgcn_sched_barrier(0);

        __builtin_amdgcn_s_setprio(1);
        #pragma unroll
        for (int fi=0; fi<8; ++fi)
            #pragma unroll
            for (int fj=0; fj<4; ++fj)
                acc[fi][fj] = __builtin_amdgcn_mfma_f32_16x16x32_bf16(af[fi], bfr[fj], acc[fi][fj], 0,0,0);
        __builtin_amdgcn_s_setprio(0);

        asm volatile("s_waitcnt vmcnt(0)" ::: "memory");   // STAGE(tt+1) landed
        __builtin_amdgcn_s_barrier();                      // publish writes+reads
        __builtin_amdgcn_sched_barrier(0);
    }

    float bs[4];
    #pragma unroll
    for (int fj=0;fj<4;++fj) bs[fj] = bias[n0 + wcol*64 + fj*16 + lr];

    if constexpr (MODE == 2){
        const int bb2 = m0 >> 11;
        const int l0g = m0 & (SEQ-1);
        bf16* outT = (bf16*)outp;
        #pragma unroll
        for (int fi=0; fi<8; ++fi){
            int rowl = wrow*128 + fi*16 + kq*4;
            #pragma unroll
            for (int fj=0; fj<4; ++fj){
                int col = n0 + wcol*64 + fj*16 + lr;
                union { bf16 h[4]; uint2 u; } pk;
                #pragma unroll
                for (int r=0;r<4;++r) pk.h[r] = __float2bfloat16(acc[fi][fj][r] + bs[fj]);
                *(uint2*)(outT + ((size_t)(bb2*CH + col))*SEQ + l0g + rowl) = pk.u;
            }
        }
    } else {
        #pragma unroll
        for (int fi=0; fi<8; ++fi){
            #pragma unroll
            for (int r=0;r<4;++r){
                int mg = m0 + wrow*128 + fi*16 + kq*4 + r;
                int lseq = mg & (SEQ-1);
                #pragma unroll
                for (int fj=0; fj<4; ++fj){
                    int ng = n0 + wcol*64 + fj*16 + lr;
                    float v = acc[fi][fj][r] + bs[fj];
                    if constexpr (MODE==1) v += rpb[(size_t)ng*SEQ + lseq];
                    if constexpr (MODE==3)
                        ((float*)outp)[(size_t)mg*CH + ng] = v;
                    else
                        ((bf16*)outp)[(size_t)mg*CH + ng] = __float2bfloat16(v);
                }
            }
        }
    }
}

// ---------------------------------------------------------------------------
// offset network from QT[b][ch][l], vector-loaded:
// thread (cg,jg) owns 32 channels x 8 consecutive positions; bf16x8 row loads
// (coalesced), acc[8][5] in regs; LDS reduce over 8 ch-groups; tanh -> pos.
// ---------------------------------------------------------------------------
__global__ __launch_bounds__(256)
void offsets_kernel(const bf16* __restrict__ QT, const float* __restrict__ weff,
                    const float* __restrict__ wcst, float* __restrict__ posb)
{
    __shared__ float P5R[8][272][5];   // 43520 B
    __shared__ float weffL[KW][GCH];   // 5120 B
    const int t = threadIdx.x;
    const int chunk = blockIdx.x, bg = blockIdx.y;
    const int b = bg>>2, g = bg&3;
    const int l0 = chunk*256;

    for (int i = t; i < KW*GCH; i += 256) weffL[i>>8][i&255] = weff[i];
    __syncthreads();

    const int jg = t & 31, cg = t >> 5;

    auto doblock = [&](int jb, int cgx){
        const int j0 = l0 - 8 + jb*8;
        float acc[8][KW];
        #pragma unroll
        for (int e=0;e<8;++e)
            #pragma unroll
            for (int kk=0;kk<KW;++kk) acc[e][kk] = 0.f;
        const bf16* base = QT + ((size_t)(b*CH + g*GCH + cgx*32))*SEQ;
        const bool safe = (j0 >= 0) && (j0 + 8 <= SEQ);
        if (safe){
            #pragma unroll 4
            for (int i=0;i<32;++i){
                float xv[8];
                { union { bf16x8 v; uint4 u; } cv;
                  cv.v = *(const bf16x8*)(base + (size_t)i*SEQ + j0);
                  unpack8(cv.u, xv); }
                float wk[KW];
                #pragma unroll
                for (int kk=0;kk<KW;++kk) wk[kk] = weffL[kk][cgx*32 + i];
                #pragma unroll
                for (int e=0;e<8;++e)
                    #pragma unroll
                    for (int kk=0;kk<KW;++kk) acc[e][kk] += xv[e]*wk[kk];
            }
        } else {
            for (int i=0;i<32;++i){
                float wk[KW];
                #pragma unroll
                for (int kk=0;kk<KW;++kk) wk[kk] = weffL[kk][cgx*32 + i];
                #pragma unroll
                for (int e=0;e<8;++e){
                    int j = j0 + e;
                    float xv = (j >= 0 && j < SEQ)
                             ? __bfloat162float(base[(size_t)i*SEQ + j]) : 0.f;
                    #pragma unroll
                    for (int kk=0;kk<KW;++kk) acc[e][kk] += xv*wk[kk];
                }
            }
        }
        #pragma unroll
        for (int e=0;e<8;++e)
            #pragma unroll
            for (int kk=0;kk<KW;++kk) P5R[cgx][jb*8+e][kk] = acc[e][kk];
    };

    doblock(jg, cg);                     // jb 0..31 (jpos 0..255)
    if (t < 16) doblock(32 + (t&1), t>>1);   // jb 32,33 (jpos 256..271)
    __syncthreads();

    const int lp = l0 + t;
    const float b2 = wcst[0], wb1 = wcst[1];
    float o;
    if (lp < 2){
        o = b2;
    } else {
        float s = b2 + wb1;
        #pragma unroll
        for (int kk=0;kk<KW;++kk){
            int j = lp - 4 + kk;
            if (j >= 0 && j < SEQ){
                int jp = t + 4 + kk;     // j - (l0-8) = t+4+kk
                float v = 0.f;
                #pragma unroll
                for (int c8=0;c8<8;++c8) v += P5R[c8][jp][kk];
                s += v;
            }
        }
        o = s;
    }
    float off = tanhf(o) * (float)KW;
    posb[bg*SEQ + lp] = ((float)lp + off) * (2048.0f/2051.0f) - 0.5f;
}

// ---------------------------------------------------------------------------
// bilinear zero-pad sampler from bf16 x: XS[b][l'][g*256+ci]
// ---------------------------------------------------------------------------
__global__ __launch_bounds__(256)
void sample_kernel(const bf16* __restrict__ Xbf, const float* __restrict__ posb,
                   bf16* __restrict__ XS)
{
    const int ci = threadIdx.x, bg = blockIdx.y;
    const int b = bg>>2, g = bg&3;
    const int lp0 = blockIdx.x*8;
    #pragma unroll
    for (int s8=0; s8<8; ++s8){
        int lp = lp0 + s8;
        float p  = posb[bg*SEQ + lp];
        float fl = floorf(p);
        float w1 = p - fl;
        int i0 = (int)fl;
        float v = 0.f;
        if (i0 >= 0 && i0 < SEQ)
            v += __bfloat162float(Xbf[((size_t)(b*SEQ + i0))*CH + g*GCH + ci]) * (1.f - w1);
        if (i0+1 >= 0 && i0+1 < SEQ)
            v += __bfloat162float(Xbf[((size_t)(b*SEQ + i0 + 1))*CH + g*GCH + ci]) * w1;
        XS[((size_t)(b*SEQ + lp))*CH + g*GCH + ci] = __float2bfloat16(v);
    }
}

// ---------------------------------------------------------------------------
// S = Q K^T (per head, MFMA over L with 512/wave K-split) + softmax -> P bf16
// ---------------------------------------------------------------------------
__global__ __launch_bounds__(256)
void attn_s_kernel(const bf16* __restrict__ QT, const bf16* __restrict__ KT,
                   bf16* __restrict__ Pbuf)
{
    __shared__ float Sc[64][69];
    __shared__ float red[64][4];
    __shared__ float mrow[64];
    __shared__ float sinv[64];
    const int t = threadIdx.x, w = t>>6, l = t&63;
    const int bh = blockIdx.x, b = bh>>4, h = bh&15;
    const bf16* q = QT + ((size_t)(b*CH + h*DHD))*SEQ;
    const bf16* k = KT + ((size_t)(b*CH + h*DHD))*SEQ;
    const int lr = l&15, lk = (l>>4)*8;

    f32x4 acc[4][4];
    #pragma unroll
    for (int i=0;i<4;++i)
        #pragma unroll
        for (int j=0;j<4;++j) acc[i][j] = (f32x4){0.f,0.f,0.f,0.f};

    for (int ks=0; ks<16; ++ks){
        int kp = w*512 + ks*32 + lk;
        bf16x8 af[4], bk8[4];
        #pragma unroll
        for (int i=0;i<4;++i) af[i]  = *(const bf16x8*)(q + (size_t)(i*16+lr)*SEQ + kp);
        #pragma unroll
        for (int j=0;j<4;++j) bk8[j] = *(const bf16x8*)(k + (size_t)(j*16+lr)*SEQ + kp);
        #pragma unroll
        for (int i=0;i<4;++i)
            #pragma unroll
            for (int j=0;j<4;++j)
                acc[i][j] = __builtin_amdgcn_mfma_f32_16x16x32_bf16(af[i], bk8[j], acc[i][j], 0,0,0);
    }
    // cross-wave reduce into Sc
    for (int wv=0; wv<4; ++wv){
        if (w == wv){
            #pragma unroll
            for (int i=0;i<4;++i)
                #pragma unroll
                for (int j=0;j<4;++j)
                    #pragma unroll
                    for (int r=0;r<4;++r){
                        int m = i*16 + (l>>4)*4 + r, n = j*16 + lr;
                        if (wv==0) Sc[m][n]  = acc[i][j][r];
                        else       Sc[m][n] += acc[i][j][r];
                    }
        }
        __syncthreads();
    }
    // softmax (scale 1/32), 4 threads per row
    const int r0 = t & 63, p = t >> 6;
    const float SCALE = 0.03125f;
    float mx = -1e30f;
    #pragma unroll
    for (int c=0;c<16;++c) mx = fmaxf(mx, Sc[r0][p*16+c]*SCALE);
    red[r0][p] = mx;
    __syncthreads();
    if (t < 64) mrow[t] = fmaxf(fmaxf(red[t][0],red[t][1]), fmaxf(red[t][2],red[t][3]));
    __syncthreads();
    float m = mrow[r0], s = 0.f;
    #pragma unroll
    for (int c=0;c<16;++c){
        float e = expf(Sc[r0][p*16+c]*SCALE - m);
        Sc[r0][p*16+c] = e;
        s += e;
    }
    red[r0][p] = s;
    __syncthreads();
    if (t < 64) sinv[t] = 1.f/(red[t][0]+red[t][1]+red[t][2]+red[t][3]);
    __syncthreads();
    float inv = sinv[r0];
    union { bf16 b[8]; uint4 u; } p0, p1;
    #pragma unroll
    for (int e=0;e<8;++e){
        p0.b[e] = __float2bfloat16(Sc[r0][p*16+e]*inv);
        p1.b[e] = __float2bfloat16(Sc[r0][p*16+8+e]*inv);
    }
    bf16* dst = Pbuf + (size_t)bh*4096 + r0*64 + p*16;
    *(uint4*)dst       = p0.u;
    *(uint4*)(dst + 8) = p1.u;
}

// ---------------------------------------------------------------------------
// F[b][l][h*64+i] = sum_j P[i][j] V[b][l][h*64+j]  (MFMA, V natural layout)
// ---------------------------------------------------------------------------
__global__ __launch_bounds__(256)
void attn_pv_kernel(const bf16* __restrict__ Pbuf, const bf16* __restrict__ V,
                    bf16* __restrict__ F)
{
    __shared__ __bf16 Pl[64][72];
    const int t = threadIdx.x, w = t>>6, l = t&63;
    const int chunk = blockIdx.x, bh = blockIdx.y;
    const int b = bh>>4, h = bh&15;
    {
        int row = t>>2, coff = (t&3)*16;
        const bf16* src = Pbuf + (size_t)bh*4096 + row*64 + coff;
        *(uint4*)&Pl[row][coff]   = *(const uint4*)src;
        *(uint4*)&Pl[row][coff+8] = *(const uint4*)(src+8);
    }
    __syncthreads();
    const int lr = l&15, lk = (l>>4)*8;
    const int lw = chunk*256 + w*64;

    f32x4 acc[4][4];
    #pragma unroll
    for (int i=0;i<4;++i)
        #pragma unroll
        for (int j=0;j<4;++j) acc[i][j] = (f32x4){0.f,0.f,0.f,0.f};

    #pragma unroll
    for (int ks=0; ks<2; ++ks){
        bf16x8 pf[4], vf[4];
        #pragma unroll
        for (int ni=0;ni<4;++ni) pf[ni] = *(const bf16x8*)&Pl[ni*16+lr][ks*32+lk];
        #pragma unroll
        for (int mi=0;mi<4;++mi)
            vf[mi] = *(const bf16x8*)(V + ((size_t)(b*SEQ + lw + mi*16 + lr))*CH + h*DHD + ks*32 + lk);
        #pragma unroll
        for (int mi=0;mi<4;++mi)
            #pragma unroll
            for (int ni=0;ni<4;++ni)
                acc[mi][ni] = __builtin_amdgcn_mfma_f32_16x16x32_bf16(vf[mi], pf[ni], acc[mi][ni], 0,0,0);
    }
    #pragma unroll
    for (int mi=0;mi<4;++mi){
        #pragma unroll
        for (int r=0;r<4;++r){
            int lpos = lw + mi*16 + (l>>4)*4 + r;
            #pragma unroll
            for (int ni=0;ni<4;++ni)
                F[((size_t)(b*SEQ + lpos))*CH + h*DHD + ni*16 + lr] =
                    __float2bfloat16(acc[mi][ni][r]);
        }
    }
}

// ---------------------------------------------------------------------------
extern "C" void kernel_launch(void* const* d_in, const int* in_sizes, int n_in,
                              void* d_out, int out_size, void* d_ws, size_t ws_size,
                              hipStream_t stream)
{
    const float* x   = (const float*)d_in[0];
    const float* Wq  = (const float*)d_in[1];
    const float* bq  = (const float*)d_in[2];
    const float* Wk  = (const float*)d_in[3];
    const float* bk  = (const float*)d_in[4];
    const float* Wv  = (const float*)d_in[5];
    const float* bv  = (const float*)d_in[6];
    const float* W1  = (const float*)d_in[7];
    const float* b1  = (const float*)d_in[8];
    const float* w2  = (const float*)d_in[9];
    const float* b2  = (const float*)d_in[10];
    const float* rpb = (const float*)d_in[11];
    const float* Wo  = (const float*)d_in[12];
    const float* bo  = (const float*)d_in[13];

    char* ws = (char*)d_ws;
    bf16*  Xbf  = (bf16*)(ws);                          // 64 MiB; later KT
    bf16*  QT   = (bf16*)(ws + (size_t) 67108864);      // 64 MiB [b][ch][l]
    bf16*  XS   = (bf16*)(ws + (size_t)134217728);      // 64 MiB; later F
    bf16*  VB   = (bf16*)(ws + (size_t)201326592);      // 64 MiB
    bf16*  Pbuf = (bf16*)(ws + (size_t)268435456);      // 2 MiB
    bf16*  wslot= (bf16*)(ws + (size_t)270532608);      // 2 MiB
    float* posb = (float*)(ws + (size_t)272629760);     // 512 KiB
    float* weff = (float*)(ws + (size_t)273154048);
    float* wcst = (float*)(ws + (size_t)273159168);
    bf16*  KT = Xbf;     // Xbf dead after sample_kernel
    bf16*  Fb = XS;      // XS dead after K/V GEMMs

    prep_weff_kernel<<<dim3(KW), dim3(GCH), 0, stream>>>(W1, b1, w2, b2, weff, wcst);
    cvt_kernel<<<dim3(MROWS*CH/8/256), 256, 0, stream>>>(x, Xbf, MROWS*CH);

    cvt_kernel<<<dim3(CH*CH/8/256), 256, 0, stream>>>(Wq, wslot, CH*CH);
    gemm256_kernel<2><<<dim3(512), 512, 0, stream>>>(Xbf, wslot, bq, nullptr, QT);

    offsets_kernel<<<dim3(SEQ/256, NBG), 256, 0, stream>>>(QT, weff, wcst, posb);
    sample_kernel<<<dim3(SEQ/8, NBG), 256, 0, stream>>>(Xbf, posb, XS);

    cvt_kernel<<<dim3(CH*CH/8/256), 256, 0, stream>>>(Wk, wslot, CH*CH);
    gemm256_kernel<2><<<dim3(512), 512, 0, stream>>>(XS, wslot, bk, nullptr, KT);

    cvt_kernel<<<dim3(CH*CH/8/256), 256, 0, stream>>>(Wv, wslot, CH*CH);
    gemm256_kernel<1><<<dim3(512), 512, 0, stream>>>(XS, wslot, bv, rpb, VB);

    attn_s_kernel<<<dim3(NBH), 256, 0, stream>>>(QT, KT, Pbuf);
    attn_pv_kernel<<<dim3(8, NBH), 256, 0, stream>>>(Pbuf, VB, Fb);

    cvt_kernel<<<dim3(CH*CH/8/256), 256, 0, stream>>>(Wo, wslot, CH*CH);
    gemm256_kernel<3><<<dim3(512), 512, 0, stream>>>(Fb, wslot, bo, nullptr, (float*)d_out);
}

// Round 11
// 593.370 us; speedup vs baseline: 5.0241x; 5.0241x over previous
//
#include <hip/hip_runtime.h>
#include <hip/hip_bf16.h>
#include <stdint.h>

#define BATCH 16
#define SEQ   2048
#define CH    1024
#define NH    16
#define NG    4
#define KW    5
#define GCH   256
#define DHD   64
#define NBG   (BATCH*NG)   // 64
#define NBH   (BATCH*NH)   // 256
#define MROWS (BATCH*SEQ)  // 32768

typedef __hip_bfloat16 bf16;
typedef float f32x4 __attribute__((ext_vector_type(4)));
typedef __bf16 bf16x8 __attribute__((ext_vector_type(8)));

__device__ __forceinline__ void unpack8(uint4 r, float* f){
    uint32_t w0=r.x,w1=r.y,w2=r.z,w3=r.w;
    f[0]=__uint_as_float(w0<<16); f[1]=__uint_as_float(w0&0xffff0000u);
    f[2]=__uint_as_float(w1<<16); f[3]=__uint_as_float(w1&0xffff0000u);
    f[4]=__uint_as_float(w2<<16); f[5]=__uint_as_float(w2&0xffff0000u);
    f[6]=__uint_as_float(w3<<16); f[7]=__uint_as_float(w3&0xffff0000u);
}

// ---------------------------------------------------------------------------
// fp32 -> bf16 convert, 8 elems/thread
// ---------------------------------------------------------------------------
__global__ __launch_bounds__(256)
void cvt_kernel(const float* __restrict__ in, bf16* __restrict__ out, int n)
{
    int i = (blockIdx.x*256 + threadIdx.x)*8;
    if (i >= n) return;
    float4 f0 = *(const float4*)(in+i);
    float4 f1 = *(const float4*)(in+i+4);
    union { bf16 b[8]; uint4 u; } pk;
    pk.b[0]=__float2bfloat16(f0.x); pk.b[1]=__float2bfloat16(f0.y);
    pk.b[2]=__float2bfloat16(f0.z); pk.b[3]=__float2bfloat16(f0.w);
    pk.b[4]=__float2bfloat16(f1.x); pk.b[5]=__float2bfloat16(f1.y);
    pk.b[6]=__float2bfloat16(f1.z); pk.b[7]=__float2bfloat16(f1.w);
    *(uint4*)(out+i) = pk.u;
}

// ---------------------------------------------------------------------------
// Weff[kk][cj] = sum_co w2[co] * W1[co][cj][kk];  wcst = {b2, dot(w2,b1)}
// ---------------------------------------------------------------------------
__global__ void prep_weff_kernel(const float* __restrict__ W1, const float* __restrict__ b1,
                                 const float* __restrict__ w2, const float* __restrict__ b2,
                                 float* __restrict__ weff, float* __restrict__ wcst)
{
    int kk = blockIdx.x;          // 0..4
    int cj = threadIdx.x;         // 0..255
    float s = 0.f;
    for (int co=0; co<GCH; ++co)
        s += w2[co] * W1[((size_t)co*GCH + cj)*KW + kk];
    weff[kk*GCH + cj] = s;
    if (kk==0 && cj==0){
        float sb = 0.f;
        for (int co=0; co<GCH; ++co) sb += w2[co]*b1[co];
        wcst[0] = b2[0];
        wcst[1] = sb;
    }
}

// ---------------------------------------------------------------------------
// 256x256-tile MFMA GEMM, BK=64, 2 LDS buffers (128 KiB), round-8 rotation,
// but with inner-loop waitcnt pins REMOVED (m141: order-pinning defeats the
// compiler's counted-lgkmcnt ds_read<->MFMA interleave; m97 shows hipcc
// emits lgkmcnt(4/3/1/0) itself when left alone).
//   iter t: STAGE(t+1 -> buf[cur^1]); sched_barrier   (pin staging issue early)
//           ds_read buf[cur] (swizzled) + 64 MFMA     (UNPINNED - compiler
//                                                      software-pipelines)
//           lgkmcnt(0) [post-MFMA, off critical path]; vmcnt(0); s_barrier
// Race-free: the single barrier is preceded in EVERY wave by vmcnt(0) (my
// STAGE(t+1) writes landed) and lgkmcnt(0) (my reads of buf[cur] complete),
// so after it: next iter may read buf[cur^1] and overwrite buf[cur].
// T2 swizzle byte^=((row&7)<<4) on 128B rows (round-8-measured 0 conflicts),
// same involution on staging global source (gload_lds dest stays linear).
// T1: 4 column-blocks of each A-panel grouped per XCD.
// MODE: 1 = bf16 [m][n]+rpb, 2 = bf16 transposed [b][n][l], 3 = f32 [m][n].
// ---------------------------------------------------------------------------
template<int MODE>
__global__ __launch_bounds__(512, 2)
void gemm256_kernel(const bf16* __restrict__ A, const bf16* __restrict__ Wb,
                    const float* __restrict__ bias, const float* __restrict__ rpb,
                    void* __restrict__ outp)
{
    __shared__ __bf16 SM[2*32768];   // 2 x (A 16384 + B 16384 elems) = 128 KiB
    const int t = threadIdx.x;
    const int w = t>>6, l = t&63;
    const int wrow = w>>2, wcol = w&3;     // 2 x 4 waves, 128x64 out each
    const int lr = l&15, kq = l>>4;        // kq: 0..3, 8-elem k sub-slot

    const int lin = blockIdx.x;            // 0..511
    const int xcd = lin&7, sblk = lin>>3;  // sblk: 0..63
    const int m0 = (xcd*16 + (sblk>>2))*256;
    const int n0 = (sblk&3)*256;

    const bf16* Ag = A  + (size_t)m0*CH;
    const bf16* Bg = Wb + (size_t)n0*CH;

    // staging: linear LDS byte o holds global element at e = o ^ (((o>>7)&7)<<4)
    int srow[4], scol[4];
    #pragma unroll
    for (int r=0;r<4;++r){
        int o = (t + 512*r)*16;
        int e = o ^ (((o>>7)&7)<<4);
        srow[r] = e>>7;            // 128B rows (64 bf16)
        scol[r] = (e&127)>>1;
    }

    auto STAGE = [&](int tile, int buf){
        const int kt = tile*64;
        __bf16* ab = SM + buf*32768;
        __bf16* bb = ab + 16384;
        #pragma unroll
        for (int r=0;r<4;++r){
            __builtin_amdgcn_global_load_lds(
                (const __attribute__((address_space(1))) void*)(Ag + (size_t)srow[r]*CH + kt + scol[r]),
                (__attribute__((address_space(3))) void*)(ab + w*512 + r*4096), 16, 0, 0);
            __builtin_amdgcn_global_load_lds(
                (const __attribute__((address_space(1))) void*)(Bg + (size_t)srow[r]*CH + kt + scol[r]),
                (__attribute__((address_space(3))) void*)(bb + w*512 + r*4096), 16, 0, 0);
        }
    };

    f32x4 acc[8][4];
    #pragma unroll
    for (int i=0;i<8;++i)
        #pragma unroll
        for (int j=0;j<4;++j) acc[i][j] = (f32x4){0.f,0.f,0.f,0.f};

    STAGE(0, 0);
    asm volatile("s_waitcnt vmcnt(0)" ::: "memory");
    __builtin_amdgcn_s_barrier();

    const int NT = CH/64;   // 16
    for (int tt=0; tt<NT; ++tt){
        const int cur = tt&1;
        if (tt+1 < NT) STAGE(tt+1, cur^1);           // issue-early prefetch
        __builtin_amdgcn_sched_barrier(0);           // keep staging issue first

        const __bf16* As_ = SM + cur*32768;
        const __bf16* Bs_ = As_ + 16384;
        // UNPINNED body: compiler inserts counted lgkmcnt between ds_read
        // and consuming MFMA (m97 behavior) and software-pipelines ks.
        #pragma unroll
        for (int ks=0; ks<2; ++ks){
            bf16x8 af[8], bfr[4];
            #pragma unroll
            for (int fi=0; fi<8; ++fi){
                int row = wrow*128 + fi*16 + lr;
                int byte = row*128 + ks*64 + kq*16;
                byte ^= (row&7)<<4;
                af[fi] = *(const bf16x8*)(As_ + (byte>>1));
            }
            #pragma unroll
            for (int fj=0; fj<4; ++fj){
                int row = wcol*64 + fj*16 + lr;
                int byte = row*128 + ks*64 + kq*16;
                byte ^= (row&7)<<4;
                bfr[fj] = *(const bf16x8*)(Bs_ + (byte>>1));
            }
            #pragma unroll
            for (int fi=0; fi<8; ++fi)
                #pragma unroll
                for (int fj=0; fj<4; ++fj)
                    acc[fi][fj] = __builtin_amdgcn_mfma_f32_16x16x32_bf16(af[fi], bfr[fj], acc[fi][fj], 0,0,0);
        }
        // end-of-tile publish (off critical path: reads already consumed)
        asm volatile("s_waitcnt lgkmcnt(0)" ::: "memory");
        asm volatile("s_waitcnt vmcnt(0)" ::: "memory");
        __builtin_amdgcn_s_barrier();
    }

    float bs[4];
    #pragma unroll
    for (int fj=0;fj<4;++fj) bs[fj] = bias[n0 + wcol*64 + fj*16 + lr];

    if constexpr (MODE == 2){
        const int bb2 = m0 >> 11;
        const int l0g = m0 & (SEQ-1);
        bf16* outT = (bf16*)outp;
        #pragma unroll
        for (int fi=0; fi<8; ++fi){
            int rowl = wrow*128 + fi*16 + kq*4;
            #pragma unroll
            for (int fj=0; fj<4; ++fj){
                int col = n0 + wcol*64 + fj*16 + lr;
                union { bf16 h[4]; uint2 u; } pk;
                #pragma unroll
                for (int r=0;r<4;++r) pk.h[r] = __float2bfloat16(acc[fi][fj][r] + bs[fj]);
                *(uint2*)(outT + ((size_t)(bb2*CH + col))*SEQ + l0g + rowl) = pk.u;
            }
        }
    } else {
        #pragma unroll
        for (int fi=0; fi<8; ++fi){
            #pragma unroll
            for (int r=0;r<4;++r){
                int mg = m0 + wrow*128 + fi*16 + kq*4 + r;
                int lseq = mg & (SEQ-1);
                #pragma unroll
                for (int fj=0; fj<4; ++fj){
                    int ng = n0 + wcol*64 + fj*16 + lr;
                    float v = acc[fi][fj][r] + bs[fj];
                    if constexpr (MODE==1) v += rpb[(size_t)ng*SEQ + lseq];
                    if constexpr (MODE==3)
                        ((float*)outp)[(size_t)mg*CH + ng] = v;
                    else
                        ((bf16*)outp)[(size_t)mg*CH + ng] = __float2bfloat16(v);
                }
            }
        }
    }
}

// ---------------------------------------------------------------------------
// offset network from QT[b][ch][l], vector-loaded (round-8 verified)
// ---------------------------------------------------------------------------
__global__ __launch_bounds__(256)
void offsets_kernel(const bf16* __restrict__ QT, const float* __restrict__ weff,
                    const float* __restrict__ wcst, float* __restrict__ posb)
{
    __shared__ float P5R[8][272][5];   // 43520 B
    __shared__ float weffL[KW][GCH];   // 5120 B
    const int t = threadIdx.x;
    const int chunk = blockIdx.x, bg = blockIdx.y;
    const int b = bg>>2, g = bg&3;
    const int l0 = chunk*256;

    for (int i = t; i < KW*GCH; i += 256) weffL[i>>8][i&255] = weff[i];
    __syncthreads();

    const int jg = t & 31, cg = t >> 5;

    auto doblock = [&](int jb, int cgx){
        const int j0 = l0 - 8 + jb*8;
        float acc[8][KW];
        #pragma unroll
        for (int e=0;e<8;++e)
            #pragma unroll
            for (int kk=0;kk<KW;++kk) acc[e][kk] = 0.f;
        const bf16* base = QT + ((size_t)(b*CH + g*GCH + cgx*32))*SEQ;
        const bool safe = (j0 >= 0) && (j0 + 8 <= SEQ);
        if (safe){
            #pragma unroll 4
            for (int i=0;i<32;++i){
                float xv[8];
                { union { bf16x8 v; uint4 u; } cv;
                  cv.v = *(const bf16x8*)(base + (size_t)i*SEQ + j0);
                  unpack8(cv.u, xv); }
                float wk[KW];
                #pragma unroll
                for (int kk=0;kk<KW;++kk) wk[kk] = weffL[kk][cgx*32 + i];
                #pragma unroll
                for (int e=0;e<8;++e)
                    #pragma unroll
                    for (int kk=0;kk<KW;++kk) acc[e][kk] += xv[e]*wk[kk];
            }
        } else {
            for (int i=0;i<32;++i){
                float wk[KW];
                #pragma unroll
                for (int kk=0;kk<KW;++kk) wk[kk] = weffL[kk][cgx*32 + i];
                #pragma unroll
                for (int e=0;e<8;++e){
                    int j = j0 + e;
                    float xv = (j >= 0 && j < SEQ)
                             ? __bfloat162float(base[(size_t)i*SEQ + j]) : 0.f;
                    #pragma unroll
                    for (int kk=0;kk<KW;++kk) acc[e][kk] += xv*wk[kk];
                }
            }
        }
        #pragma unroll
        for (int e=0;e<8;++e)
            #pragma unroll
            for (int kk=0;kk<KW;++kk) P5R[cgx][jb*8+e][kk] = acc[e][kk];
    };

    doblock(jg, cg);                     // jb 0..31 (jpos 0..255)
    if (t < 16) doblock(32 + (t&1), t>>1);   // jb 32,33 (jpos 256..271)
    __syncthreads();

    const int lp = l0 + t;
    const float b2 = wcst[0], wb1 = wcst[1];
    float o;
    if (lp < 2){
        o = b2;
    } else {
        float s = b2 + wb1;
        #pragma unroll
        for (int kk=0;kk<KW;++kk){
            int j = lp - 4 + kk;
            if (j >= 0 && j < SEQ){
                int jp = t + 4 + kk;     // j - (l0-8) = t+4+kk
                float v = 0.f;
                #pragma unroll
                for (int c8=0;c8<8;++c8) v += P5R[c8][jp][kk];
                s += v;
            }
        }
        o = s;
    }
    float off = tanhf(o) * (float)KW;
    posb[bg*SEQ + lp] = ((float)lp + off) * (2048.0f/2051.0f) - 0.5f;
}

// ---------------------------------------------------------------------------
// bilinear zero-pad sampler from bf16 x: XS[b][l'][g*256+ci]
// ---------------------------------------------------------------------------
__global__ __launch_bounds__(256)
void sample_kernel(const bf16* __restrict__ Xbf, const float* __restrict__ posb,
                   bf16* __restrict__ XS)
{
    const int ci = threadIdx.x, bg = blockIdx.y;
    const int b = bg>>2, g = bg&3;
    const int lp0 = blockIdx.x*8;
    #pragma unroll
    for (int s8=0; s8<8; ++s8){
        int lp = lp0 + s8;
        float p  = posb[bg*SEQ + lp];
        float fl = floorf(p);
        float w1 = p - fl;
        int i0 = (int)fl;
        float v = 0.f;
        if (i0 >= 0 && i0 < SEQ)
            v += __bfloat162float(Xbf[((size_t)(b*SEQ + i0))*CH + g*GCH + ci]) * (1.f - w1);
        if (i0+1 >= 0 && i0+1 < SEQ)
            v += __bfloat162float(Xbf[((size_t)(b*SEQ + i0 + 1))*CH + g*GCH + ci]) * w1;
        XS[((size_t)(b*SEQ + lp))*CH + g*GCH + ci] = __float2bfloat16(v);
    }
}

// ---------------------------------------------------------------------------
// FUSED attention per (b,h): S = QK^T (MFMA, K-split over L), softmax,
// P packed bf16 in LDS, then PV over all 8 l-chunks (V natural layout).
// Removes the Pbuf global roundtrip and the 2048-block attn_pv launch.
// ---------------------------------------------------------------------------
__global__ __launch_bounds__(256)
void attn_fused_kernel(const bf16* __restrict__ QT, const bf16* __restrict__ KT,
                       const bf16* __restrict__ V, bf16* __restrict__ F)
{
    __shared__ float Sc[64][69];
    __shared__ float red[64][4];
    __shared__ float mrow[64];
    __shared__ float sinv[64];
    __shared__ __bf16 Pl[64][72];
    const int t = threadIdx.x, w = t>>6, l = t&63;
    const int bh = blockIdx.x, b = bh>>4, h = bh&15;
    const bf16* q = QT + ((size_t)(b*CH + h*DHD))*SEQ;
    const bf16* k = KT + ((size_t)(b*CH + h*DHD))*SEQ;
    const int lr = l&15, lk = (l>>4)*8;

    f32x4 acc[4][4];
    #pragma unroll
    for (int i=0;i<4;++i)
        #pragma unroll
        for (int j=0;j<4;++j) acc[i][j] = (f32x4){0.f,0.f,0.f,0.f};

    for (int ks=0; ks<16; ++ks){
        int kp = w*512 + ks*32 + lk;
        bf16x8 af[4], bk8[4];
        #pragma unroll
        for (int i=0;i<4;++i) af[i]  = *(const bf16x8*)(q + (size_t)(i*16+lr)*SEQ + kp);
        #pragma unroll
        for (int j=0;j<4;++j) bk8[j] = *(const bf16x8*)(k + (size_t)(j*16+lr)*SEQ + kp);
        #pragma unroll
        for (int i=0;i<4;++i)
            #pragma unroll
            for (int j=0;j<4;++j)
                acc[i][j] = __builtin_amdgcn_mfma_f32_16x16x32_bf16(af[i], bk8[j], acc[i][j], 0,0,0);
    }
    // cross-wave reduce into Sc
    for (int wv=0; wv<4; ++wv){
        if (w == wv){
            #pragma unroll
            for (int i=0;i<4;++i)
                #pragma unroll
                for (int j=0;j<4;++j)
                    #pragma unroll
                    for (int r=0;r<4;++r){
                        int m = i*16 + (l>>4)*4 + r, n = j*16 + lr;
                        if (wv==0) Sc[m][n]  = acc[i][j][r];
                        else       Sc[m][n] += acc[i][j][r];
                    }
        }
        __syncthreads();
    }
    // softmax (scale 1/32), 4 threads per row
    const int r0 = t & 63, p = t >> 6;
    const float SCALE = 0.03125f;
    float mx = -1e30f;
    #pragma unroll
    for (int c=0;c<16;++c) mx = fmaxf(mx, Sc[r0][p*16+c]*SCALE);
    red[r0][p] = mx;
    __syncthreads();
    if (t < 64) mrow[t] = fmaxf(fmaxf(red[t][0],red[t][1]), fmaxf(red[t][2],red[t][3]));
    __syncthreads();
    float m = mrow[r0], s = 0.f;
    #pragma unroll
    for (int c=0;c<16;++c){
        float e = expf(Sc[r0][p*16+c]*SCALE - m);
        Sc[r0][p*16+c] = e;
        s += e;
    }
    red[r0][p] = s;
    __syncthreads();
    if (t < 64) sinv[t] = 1.f/(red[t][0]+red[t][1]+red[t][2]+red[t][3]);
    __syncthreads();
    float inv = sinv[r0];
    #pragma unroll
    for (int e=0;e<16;++e)
        Pl[r0][p*16+e] = (__bf16)__float2bfloat16(Sc[r0][p*16+e]*inv);
    __syncthreads();

    // PV: P-frags hoisted (invariant across chunks), V from global
    const size_t base = (size_t)b*SEQ*CH + (size_t)h*DHD;
    bf16x8 pf[4][2];
    #pragma unroll
    for (int ks=0; ks<2; ++ks)
        #pragma unroll
        for (int ni=0;ni<4;++ni)
            pf[ni][ks] = *(const bf16x8*)&Pl[ni*16+lr][ks*32+lk];

    for (int c8=0; c8<8; ++c8){
        const int lw = c8*256 + w*64;
        f32x4 po[4][4];
        #pragma unroll
        for (int i=0;i<4;++i)
            #pragma unroll
            for (int j=0;j<4;++j) po[i][j] = (f32x4){0.f,0.f,0.f,0.f};
        #pragma unroll
        for (int ks=0; ks<2; ++ks){
            bf16x8 vf[4];
            #pragma unroll
            for (int mi=0;mi<4;++mi)
                vf[mi] = *(const bf16x8*)(V + base + (size_t)(lw + mi*16 + lr)*CH + h*0 + ks*32 + lk);
            #pragma unroll
            for (int mi=0;mi<4;++mi)
                #pragma unroll
                for (int ni=0;ni<4;++ni)
                    po[mi][ni] = __builtin_amdgcn_mfma_f32_16x16x32_bf16(vf[mi], pf[ni][ks], po[mi][ni], 0,0,0);
        }
        #pragma unroll
        for (int mi=0;mi<4;++mi){
            #pragma unroll
            for (int r=0;r<4;++r){
                int lpos = lw + mi*16 + (l>>4)*4 + r;
                #pragma unroll
                for (int ni=0;ni<4;++ni)
                    F[base + (size_t)lpos*CH + ni*16 + lr] =
                        __float2bfloat16(po[mi][ni][r]);
            }
        }
    }
}

// ---------------------------------------------------------------------------
extern "C" void kernel_launch(void* const* d_in, const int* in_sizes, int n_in,
                              void* d_out, int out_size, void* d_ws, size_t ws_size,
                              hipStream_t stream)
{
    const float* x   = (const float*)d_in[0];
    const float* Wq  = (const float*)d_in[1];
    const float* bq  = (const float*)d_in[2];
    const float* Wk  = (const float*)d_in[3];
    const float* bk  = (const float*)d_in[4];
    const float* Wv  = (const float*)d_in[5];
    const float* bv  = (const float*)d_in[6];
    const float* W1  = (const float*)d_in[7];
    const float* b1  = (const float*)d_in[8];
    const float* w2  = (const float*)d_in[9];
    const float* b2  = (const float*)d_in[10];
    const float* rpb = (const float*)d_in[11];
    const float* Wo  = (const float*)d_in[12];
    const float* bo  = (const float*)d_in[13];

    char* ws = (char*)d_ws;
    bf16*  Xbf  = (bf16*)(ws);                          // 64 MiB; later KT
    bf16*  QT   = (bf16*)(ws + (size_t) 67108864);      // 64 MiB [b][ch][l]
    bf16*  XS   = (bf16*)(ws + (size_t)134217728);      // 64 MiB; later F
    bf16*  VB   = (bf16*)(ws + (size_t)201326592);      // 64 MiB
    bf16*  wslot= (bf16*)(ws + (size_t)270532608);      // 2 MiB
    float* posb = (float*)(ws + (size_t)272629760);     // 512 KiB
    float* weff = (float*)(ws + (size_t)273154048);
    float* wcst = (float*)(ws + (size_t)273159168);
    bf16*  KT = Xbf;     // Xbf dead after sample_kernel
    bf16*  Fb = XS;      // XS dead after K/V GEMMs

    prep_weff_kernel<<<dim3(KW), dim3(GCH), 0, stream>>>(W1, b1, w2, b2, weff, wcst);
    cvt_kernel<<<dim3(MROWS*CH/8/256), 256, 0, stream>>>(x, Xbf, MROWS*CH);

    cvt_kernel<<<dim3(CH*CH/8/256), 256, 0, stream>>>(Wq, wslot, CH*CH);
    gemm256_kernel<2><<<dim3(512), 512, 0, stream>>>(Xbf, wslot, bq, nullptr, QT);

    offsets_kernel<<<dim3(SEQ/256, NBG), 256, 0, stream>>>(QT, weff, wcst, posb);
    sample_kernel<<<dim3(SEQ/8, NBG), 256, 0, stream>>>(Xbf, posb, XS);

    cvt_kernel<<<dim3(CH*CH/8/256), 256, 0, stream>>>(Wk, wslot, CH*CH);
    gemm256_kernel<2><<<dim3(512), 512, 0, stream>>>(XS, wslot, bk, nullptr, KT);

    cvt_kernel<<<dim3(CH*CH/8/256), 256, 0, stream>>>(Wv, wslot, CH*CH);
    gemm256_kernel<1><<<dim3(512), 512, 0, stream>>>(XS, wslot, bv, rpb, VB);

    attn_fused_kernel<<<dim3(NBH), 256, 0, stream>>>(QT, KT, VB, Fb);

    cvt_kernel<<<dim3(CH*CH/8/256), 256, 0, stream>>>(Wo, wslot, CH*CH);
    gemm256_kernel<3><<<dim3(512), 512, 0, stream>>>(Fb, wslot, bo, nullptr, (float*)d_out);
}